// Round 3
// baseline (2391.680 us; speedup 1.0000x reference)
//
#include <hip/hip_runtime.h>
#include <hip/hip_fp16.h>

#define BATCH 32
#define SEQ   1024
#define DIM   512

typedef _Float16 f16x8 __attribute__((ext_vector_type(8)));
typedef float    f32x4 __attribute__((ext_vector_type(4)));
typedef unsigned int u32x4 __attribute__((ext_vector_type(4)));

union UU4 { uint4 s; u32x4 v; };

static __device__ __forceinline__ float tanh_fast(float x) {
    float e = __expf(2.0f * x);
    return 1.0f - 2.0f / (e + 1.0f);
}

// Barrier draining only LDS ops; global loads/stores stay in flight (they
// ride vmcnt, which we deliberately do not wait on).
#define LDS_BARRIER() asm volatile("s_waitcnt lgkmcnt(0)\n\ts_barrier" ::: "memory")

// ---------------------------------------------------------------------------
// Pack a 512x512 fp32 row-major W into fp16 MFMA B-fragment layout:
//   Wp[((k>>5)*512 + n)*32 + ((k>>3)&3)*8 + (k&7)] = W[k][n]
// ---------------------------------------------------------------------------
__global__ void pack_w(const float* __restrict__ W, __half* __restrict__ Wp) {
    int id = blockIdx.x * blockDim.x + threadIdx.x;   // 0 .. 262143
    int n = id & 511;
    int k = id >> 9;
    Wp[((k >> 5) * 512 + n) * 32 + ((k >> 3) & 3) * 8 + (k & 7)] = __float2half(W[k * 512 + n]);
}

// ---------------------------------------------------------------------------
// Kernel 1 (v3): xw = x @ W_xh + b. Grid (2, 512): 64 rows x 256 cols per
// block, acc[16] f32x4 = 64 VGPRs (R2's acc[32]=128 spilled/serialized).
// X re-read 2x (was 8x in R1, 1x attempt in R2 regressed on reg pressure).
// ---------------------------------------------------------------------------
__global__ __launch_bounds__(256) void gemm_xw(const float* __restrict__ X,
                                               const __half* __restrict__ Wp,
                                               const float* __restrict__ bias,
                                               float* __restrict__ out) {
    const int nb   = blockIdx.x;          // 0..1   (256-col half)
    const int mb   = blockIdx.y;          // 0..511 (64-row stripe)
    const int lane = threadIdx.x & 63;
    const int wave = threadIdx.x >> 6;
    const int q    = lane >> 4;
    const int r16  = lane & 15;
    const int row  = mb * 64 + wave * 16 + r16;

    const float4* Xf4  = (const float4*)X;
    const uint4*  WpU4 = (const uint4*)Wp;

    f32x4 acc[16];
    #pragma unroll
    for (int nt = 0; nt < 16; ++nt) acc[nt] = (f32x4){0.f, 0.f, 0.f, 0.f};

    #pragma unroll 2
    for (int kb = 0; kb < 16; ++kb) {
        float4 a0 = Xf4[row * 128 + kb * 8 + q * 2];
        float4 a1 = Xf4[row * 128 + kb * 8 + q * 2 + 1];
        f16x8 af;
        af[0] = (_Float16)a0.x; af[1] = (_Float16)a0.y;
        af[2] = (_Float16)a0.z; af[3] = (_Float16)a0.w;
        af[4] = (_Float16)a1.x; af[5] = (_Float16)a1.y;
        af[6] = (_Float16)a1.z; af[7] = (_Float16)a1.w;
        #pragma unroll
        for (int nt = 0; nt < 16; ++nt) {
            int col = nb * 256 + nt * 16 + r16;
            UU4 tmp; tmp.s = WpU4[(kb * 512 + col) * 4 + q];
            acc[nt] = __builtin_amdgcn_mfma_f32_16x16x32_f16(
                af, __builtin_bit_cast(f16x8, tmp.v), acc[nt], 0, 0, 0);
        }
    }

    const int rbase = mb * 64 + wave * 16 + q * 4;
    #pragma unroll
    for (int nt = 0; nt < 16; ++nt) {
        int col = nb * 256 + nt * 16 + r16;
        float bv = bias[col];
        #pragma unroll
        for (int rr = 0; rr < 4; ++rr) {
            out[(size_t)(rbase + rr) * 512 + col] = acc[nt][rr] + bv;
        }
    }
}

// ---------------------------------------------------------------------------
// Kernel 2 (v4): recurrence, 512 threads = 8 waves = 2 waves/SIMD.
// R2 counters: active-CU MfmaUtil 67% -> MFMA busy ~2060 cyc of the 3071-cyc
// step; ~1000 cyc exposed. Main suspect: LDS pipe ~1920 cyc/step (256 x
// ds_read_b128-class wave-instrs per CU). v4 moves half the streamed B from
// LDS to global/L2: W_hh fragments are CONSTANT, so kb 12..13 live in an
// 8-frag register buffer reloaded right after use (WAR-only; loads ride
// vmcnt, which LDS_BARRIER doesn't drain; a full ~2500-cyc step covers the
// ~250-cyc L2 latency). LDS keeps kb 14..15 (LBS 64 KB) + h exchange.
// LDS pipe/step: 1920 -> ~1280 cyc, now under the MFMA stream.
// B layout: kb 0..11 AGPR-resident (48 frags), kb 12..13 global-streamed,
// kb 14..15 LDS-streamed.
// ---------------------------------------------------------------------------
__global__ __launch_bounds__(512, 2) void rnn_rec(const uint4* __restrict__ Wp4,
                                                  float* __restrict__ out) {
    extern __shared__ char smem[];
    uint4*  LBS = (uint4*)smem;                 // 4096 uint4 = 64 KB (kb 14..15)
    __half* hb  = (__half*)(smem + 65536);      // 2 x 512 halves (double buffer)

    const int b    = blockIdx.x;
    const int t    = threadIdx.x;    // 0..511
    const int lane = t & 63;
    const int w    = t >> 6;         // wave 0..7: owns cols [w*64, w*64+64)
    const int q    = lane >> 4;      // quad 0..3 (== this thread's N-tile)
    const int r16  = lane & 15;

    // Stage LDS-streamed B-fragments (k-blocks 14..15).
    // Read layout: LBS[j*512 + t] -> contiguous across the wave, conflict-free.
    #pragma unroll
    for (int j = 0; j < 8; ++j) {
        int kb  = 14 + (j >> 2);
        int col = w * 64 + (j & 3) * 16 + r16;
        LBS[j * 512 + t] = Wp4[(kb * 512 + col) * 4 + q];
    }

    // AGPR-resident B-fragments: k-blocks 0..11 x 4 N-tiles = 48 uint4/lane.
    u32x4 Bf[48];
    #pragma unroll
    for (int kb = 0; kb < 12; ++kb) {
        #pragma unroll
        for (int nt = 0; nt < 4; ++nt) {
            int col = w * 64 + nt * 16 + r16;
            UU4 tmp; tmp.s = Wp4[(kb * 512 + col) * 4 + q];
            Bf[kb * 4 + nt] = tmp.v;
        }
    }
    #pragma unroll
    for (int i = 0; i < 48; ++i) asm volatile("" : "+a"(Bf[i]));

    // Global-streamed B-fragments (k-blocks 12..13): per-thread constant
    // addresses; prologue load, then reload-after-use each step.
    const uint4* gp = Wp4 + ((size_t)(12 * 512 + w * 64 + r16)) * 4 + q;
    u32x4 sbuf[8];
    #pragma unroll
    for (int s = 0; s < 2; ++s) {
        #pragma unroll
        for (int nt = 0; nt < 4; ++nt) {
            UU4 tmp; tmp.s = gp[(s * 512 + nt * 16) * 4];
            sbuf[s * 4 + nt] = tmp.v;
        }
    }

    float* orow = out + (size_t)b * SEQ * DIM;
    const int c = w * 64 + q * 16 + r16;   // this thread's single output col

    // Step 0: h = tanh(xw).
    float xw = orow[c];
    float h  = tanh_fast(xw);
    orow[c] = h;
    hb[c] = __float2half(h);
    xw = orow[DIM + c];                    // value for step 1
    LDS_BARRIER();

    #pragma unroll 1
    for (int step = 1; step < SEQ; ++step) {
        orow += DIM;
        // Prefetch step+1's xw immediately: ~1.5 steps of latency budget.
        // (step 1023 reads the h_final region: in-bounds, value unused.)
        float xw_nxt = orow[DIM + c];

        const __half* ha = hb + (((step & 1) ^ 1) << 9);   // h_{t-1}

        f32x4 m[4];
        #pragma unroll
        for (int i = 0; i < 4; ++i) m[i] = (f32x4){0.f, 0.f, 0.f, 0.f};

        // LDS-streamed k-blocks (14..15) first: ds_reads fill the LDS pipe
        // while the MFMA stream spins up.
        #pragma unroll
        for (int s = 0; s < 2; ++s) {
            f16x8 af = *(const f16x8*)(ha + (14 + s) * 32 + q * 8);
            #pragma unroll
            for (int nt = 0; nt < 4; ++nt) {
                UU4 tmp; tmp.s = LBS[(s * 4 + nt) * 512 + t];
                m[nt] = __builtin_amdgcn_mfma_f32_16x16x32_f16(
                    af, __builtin_bit_cast(f16x8, tmp.v), m[nt], 0, 0, 0);
            }
        }
        // Global-streamed k-blocks (12..13): use buffer, then reload it for
        // the next step (data is constant; only a register WAR hazard).
        #pragma unroll
        for (int s = 0; s < 2; ++s) {
            f16x8 af = *(const f16x8*)(ha + (12 + s) * 32 + q * 8);
            #pragma unroll
            for (int nt = 0; nt < 4; ++nt) {
                m[nt] = __builtin_amdgcn_mfma_f32_16x16x32_f16(
                    af, __builtin_bit_cast(f16x8, sbuf[s * 4 + nt]), m[nt], 0, 0, 0);
            }
        }
        #pragma unroll
        for (int s = 0; s < 2; ++s) {
            #pragma unroll
            for (int nt = 0; nt < 4; ++nt) {
                UU4 tmp; tmp.s = gp[(s * 512 + nt * 16) * 4];
                sbuf[s * 4 + nt] = tmp.v;
            }
        }
        // AGPR-resident k-blocks (0..11).
        #pragma unroll
        for (int kb = 0; kb < 12; ++kb) {
            f16x8 af = *(const f16x8*)(ha + kb * 32 + q * 8);
            #pragma unroll
            for (int nt = 0; nt < 4; ++nt) {
                m[nt] = __builtin_amdgcn_mfma_f32_16x16x32_f16(
                    af, __builtin_bit_cast(f16x8, Bf[kb * 4 + nt]), m[nt], 0, 0, 0);
            }
        }

        // All acc rows equal (replicated A): tile q, reg 0 holds col c.
        float v = (q == 0 ? m[0][0] : q == 1 ? m[1][0] : q == 2 ? m[2][0] : m[3][0]) + xw;
        h = tanh_fast(v);

        orow[c] = h;
        __half* hw = hb + ((step & 1) << 9);
        hw[c] = __float2half(h);
        xw = xw_nxt;
        LDS_BARRIER();
    }

    float* hf = out + (size_t)BATCH * SEQ * DIM + (size_t)b * DIM;
    hf[c] = h;
}

extern "C" void kernel_launch(void* const* d_in, const int* in_sizes, int n_in,
                              void* d_out, int out_size, void* d_ws, size_t ws_size,
                              hipStream_t stream) {
    const float* X    = (const float*)d_in[0];   // [32,1024,512] fp32
    const float* Wxh  = (const float*)d_in[1];   // [512,512] fp32
    const float* Whh  = (const float*)d_in[2];   // [512,512] fp32
    const float* bias = (const float*)d_in[3];   // [512] fp32
    float* out = (float*)d_out;

    __half* WpXh = (__half*)d_ws;                          // 512 KB @ 0
    __half* WpHh = (__half*)((char*)d_ws + (512u << 10));  // 512 KB @ 512K

    (void)hipFuncSetAttribute((const void*)rnn_rec,
                              hipFuncAttributeMaxDynamicSharedMemorySize, 67584);

    pack_w<<<512, 512, 0, stream>>>(Wxh, WpXh);
    pack_w<<<512, 512, 0, stream>>>(Whh, WpHh);
    gemm_xw<<<dim3(2, 512), 256, 0, stream>>>(X, WpXh, bias, out);
    rnn_rec<<<BATCH, 512, 67584, stream>>>((const uint4*)WpHh, out);
}

// Round 4
// 1999.972 us; speedup vs baseline: 1.1959x; 1.1959x over previous
//
#include <hip/hip_runtime.h>
#include <hip/hip_fp16.h>

#define BATCH 32
#define SEQ   1024
#define DIM   512

typedef _Float16 f16x8 __attribute__((ext_vector_type(8)));
typedef float    f32x4 __attribute__((ext_vector_type(4)));
typedef unsigned int u32x4 __attribute__((ext_vector_type(4)));

union UU4 { uint4 s; u32x4 v; };

static __device__ __forceinline__ float tanh_fast(float x) {
    float e = __expf(2.0f * x);
    return 1.0f - 2.0f / (e + 1.0f);
}

// Barrier draining only LDS ops; global loads/stores stay in flight (they
// ride vmcnt, which we deliberately do not wait on). h is exchanged only
// through LDS, so lgkmcnt(0) is the full correctness requirement.
#define LDS_BARRIER() asm volatile("s_waitcnt lgkmcnt(0)\n\ts_barrier" ::: "memory")

// ---------------------------------------------------------------------------
// Pack a 512x512 fp32 row-major W into fp16 MFMA B-fragment layout:
//   Wp[((k>>5)*512 + n)*32 + ((k>>3)&3)*8 + (k&7)] = W[k][n]
// ---------------------------------------------------------------------------
__global__ void pack_w(const float* __restrict__ W, __half* __restrict__ Wp) {
    int id = blockIdx.x * blockDim.x + threadIdx.x;   // 0 .. 262143
    int n = id & 511;
    int k = id >> 9;
    Wp[((k >> 5) * 512 + n) * 32 + ((k >> 3) & 3) * 8 + (k & 7)] = __float2half(W[k * 512 + n]);
}

// ---------------------------------------------------------------------------
// Kernel 1 (v3, unchanged): xw = x @ W_xh + b. Grid (2, 512): 64 rows x 256
// cols per block, acc[16] f32x4 = 64 VGPRs. X re-read 2x. Measured: rest-of-
// total (pack+gemm) = 169 us in R3.
// ---------------------------------------------------------------------------
__global__ __launch_bounds__(256) void gemm_xw(const float* __restrict__ X,
                                               const __half* __restrict__ Wp,
                                               const float* __restrict__ bias,
                                               float* __restrict__ out) {
    const int nb   = blockIdx.x;          // 0..1   (256-col half)
    const int mb   = blockIdx.y;          // 0..511 (64-row stripe)
    const int lane = threadIdx.x & 63;
    const int wave = threadIdx.x >> 6;
    const int q    = lane >> 4;
    const int r16  = lane & 15;
    const int row  = mb * 64 + wave * 16 + r16;

    const float4* Xf4  = (const float4*)X;
    const uint4*  WpU4 = (const uint4*)Wp;

    f32x4 acc[16];
    #pragma unroll
    for (int nt = 0; nt < 16; ++nt) acc[nt] = (f32x4){0.f, 0.f, 0.f, 0.f};

    #pragma unroll 2
    for (int kb = 0; kb < 16; ++kb) {
        float4 a0 = Xf4[row * 128 + kb * 8 + q * 2];
        float4 a1 = Xf4[row * 128 + kb * 8 + q * 2 + 1];
        f16x8 af;
        af[0] = (_Float16)a0.x; af[1] = (_Float16)a0.y;
        af[2] = (_Float16)a0.z; af[3] = (_Float16)a0.w;
        af[4] = (_Float16)a1.x; af[5] = (_Float16)a1.y;
        af[6] = (_Float16)a1.z; af[7] = (_Float16)a1.w;
        #pragma unroll
        for (int nt = 0; nt < 16; ++nt) {
            int col = nb * 256 + nt * 16 + r16;
            UU4 tmp; tmp.s = WpU4[(kb * 512 + col) * 4 + q];
            acc[nt] = __builtin_amdgcn_mfma_f32_16x16x32_f16(
                af, __builtin_bit_cast(f16x8, tmp.v), acc[nt], 0, 0, 0);
        }
    }

    const int rbase = mb * 64 + wave * 16 + q * 4;
    #pragma unroll
    for (int nt = 0; nt < 16; ++nt) {
        int col = nb * 256 + nt * 16 + r16;
        float bv = bias[col];
        #pragma unroll
        for (int rr = 0; rr < 4; ++rr) {
            out[(size_t)(rbase + rr) * 512 + col] = acc[nt][rr] + bv;
        }
    }
}

// ---------------------------------------------------------------------------
// Kernel 2 (v5): recurrence, 512 threads = 8 waves = 2 waves/SIMD.
// R3's global-streaming of W regressed (per-step VALU address remat +
// vmcnt entanglement): reverted. v5 attacks the LDS pipe the safe way:
// occupancy data (R1: 8 waves resident at 320 regs/wave) proves the per-SIMD
// reg pool >= 640, so kb 12..13 move from LDS into AGPRs.
// B layout: kb 0..13 AGPR-resident (56 frags = 224 AGPR), kb 14..15 streamed
// from a 64 KB LDS image. Per-wave LDS reads/step: 32 -> 24 (8 B + 16 af);
// per-CU LDS pipe ~1550-2300 cyc, now under the 2483-cyc MFMA stream.
// Failure mode: if the pool is < 704/SIMD, occupancy halves (visible in
// counters) -> revert to 48-frag split.
// ---------------------------------------------------------------------------
__global__ __launch_bounds__(512, 2) void rnn_rec(const uint4* __restrict__ Wp4,
                                                  float* __restrict__ out) {
    extern __shared__ char smem[];
    uint4*  LBS = (uint4*)smem;                 // 4096 uint4 = 64 KB (kb 14..15)
    __half* hb  = (__half*)(smem + 65536);      // 2 x 512 halves (double buffer)

    const int b    = blockIdx.x;
    const int t    = threadIdx.x;    // 0..511
    const int lane = t & 63;
    const int w    = t >> 6;         // wave 0..7: owns cols [w*64, w*64+64)
    const int q    = lane >> 4;      // quad 0..3 (== this thread's N-tile)
    const int r16  = lane & 15;

    // Stage LDS-streamed B-fragments (k-blocks 14..15).
    // Read layout: LBS[j*512 + t] -> contiguous across the block, conflict-free
    // ds_read_b128.
    #pragma unroll
    for (int j = 0; j < 8; ++j) {
        int kb  = 14 + (j >> 2);
        int col = w * 64 + (j & 3) * 16 + r16;
        LBS[j * 512 + t] = Wp4[(kb * 512 + col) * 4 + q];
    }

    // AGPR-resident B-fragments: k-blocks 0..13 x 4 N-tiles = 56 uint4/lane
    // = 224 AGPRs (<= 256/wave AGPR limit).
    u32x4 Bf[56];
    #pragma unroll
    for (int kb = 0; kb < 14; ++kb) {
        #pragma unroll
        for (int nt = 0; nt < 4; ++nt) {
            int col = w * 64 + nt * 16 + r16;
            UU4 tmp; tmp.s = Wp4[(kb * 512 + col) * 4 + q];
            Bf[kb * 4 + nt] = tmp.v;
        }
    }
    #pragma unroll
    for (int i = 0; i < 56; ++i) asm volatile("" : "+a"(Bf[i]));

    float* orow = out + (size_t)b * SEQ * DIM;
    const int c = w * 64 + q * 16 + r16;   // this thread's single output col

    // Step 0: h = tanh(xw).
    float xw = orow[c];
    float h  = tanh_fast(xw);
    orow[c] = h;
    hb[c] = __float2half(h);
    xw = orow[DIM + c];                    // value for step 1
    LDS_BARRIER();

    #pragma unroll 1
    for (int step = 1; step < SEQ; ++step) {
        orow += DIM;
        // Prefetch step+1's xw immediately: ~1.5 steps of latency budget.
        // (step 1023 reads the h_final region: in-bounds, value unused.)
        float xw_nxt = orow[DIM + c];

        const __half* ha = hb + (((step & 1) ^ 1) << 9);   // h_{t-1}

        f32x4 m[4];
        #pragma unroll
        for (int i = 0; i < 4; ++i) m[i] = (f32x4){0.f, 0.f, 0.f, 0.f};

        // LDS-streamed k-blocks (14..15) first: ds_reads fill the LDS pipe
        // while the MFMA stream spins up.
        #pragma unroll
        for (int s = 0; s < 2; ++s) {
            f16x8 af = *(const f16x8*)(ha + (14 + s) * 32 + q * 8);
            #pragma unroll
            for (int nt = 0; nt < 4; ++nt) {
                UU4 tmp; tmp.s = LBS[(s * 4 + nt) * 512 + t];
                m[nt] = __builtin_amdgcn_mfma_f32_16x16x32_f16(
                    af, __builtin_bit_cast(f16x8, tmp.v), m[nt], 0, 0, 0);
            }
        }
        // AGPR-resident k-blocks (0..13).
        #pragma unroll
        for (int kb = 0; kb < 14; ++kb) {
            f16x8 af = *(const f16x8*)(ha + kb * 32 + q * 8);
            #pragma unroll
            for (int nt = 0; nt < 4; ++nt) {
                m[nt] = __builtin_amdgcn_mfma_f32_16x16x32_f16(
                    af, __builtin_bit_cast(f16x8, Bf[kb * 4 + nt]), m[nt], 0, 0, 0);
            }
        }

        // All acc rows equal (replicated A): tile q, reg 0 holds col c.
        float v = (q == 0 ? m[0][0] : q == 1 ? m[1][0] : q == 2 ? m[2][0] : m[3][0]) + xw;
        h = tanh_fast(v);

        orow[c] = h;
        __half* hw = hb + ((step & 1) << 9);
        hw[c] = __float2half(h);
        xw = xw_nxt;
        LDS_BARRIER();
    }

    float* hf = out + (size_t)BATCH * SEQ * DIM + (size_t)b * DIM;
    hf[c] = h;
}

extern "C" void kernel_launch(void* const* d_in, const int* in_sizes, int n_in,
                              void* d_out, int out_size, void* d_ws, size_t ws_size,
                              hipStream_t stream) {
    const float* X    = (const float*)d_in[0];   // [32,1024,512] fp32
    const float* Wxh  = (const float*)d_in[1];   // [512,512] fp32
    const float* Whh  = (const float*)d_in[2];   // [512,512] fp32
    const float* bias = (const float*)d_in[3];   // [512] fp32
    float* out = (float*)d_out;

    __half* WpXh = (__half*)d_ws;                          // 512 KB @ 0
    __half* WpHh = (__half*)((char*)d_ws + (512u << 10));  // 512 KB @ 512K

    (void)hipFuncSetAttribute((const void*)rnn_rec,
                              hipFuncAttributeMaxDynamicSharedMemorySize, 67584);

    pack_w<<<512, 512, 0, stream>>>(Wxh, WpXh);
    pack_w<<<512, 512, 0, stream>>>(Whh, WpHh);
    gemm_xw<<<dim3(2, 512), 256, 0, stream>>>(X, WpXh, bias, out);
    rnn_rec<<<BATCH, 512, 67584, stream>>>((const uint4*)WpHh, out);
}